// Round 4
// baseline (484.547 us; speedup 1.0000x reference)
//
#include <hip/hip_runtime.h>
#include <hip/hip_bf16.h>

#define N_NODES 100000
#define N_EDGES 1600000
#define NC 40
#define CAP 64               // bucket capacity; data max-degree ~45 << 64

#define NXCD 8
#define XRANGE 12500         // N_NODES / NXCD : destination slice per XCD
#define FILL_CHUNK  2048     // edges per block (256 thr x 8)
#define FILL_CHUNKS 782      // ceil(N_EDGES/FILL_CHUNK)
#define FILL_BLOCKS (NXCD * FILL_CHUNKS)   // 6256
#define MF_BLOCKS 1563       // ceil(100000 / 64): 64 rows/block = 4 waves x 16 rows

typedef _Float16 half8 __attribute__((ext_vector_type(8)));
typedef float f32x4 __attribute__((ext_vector_type(4)));

// ---- bf16 helpers (packed 2x16 in a uint) ----
__device__ __forceinline__ float bflo(unsigned u) { return __uint_as_float(u << 16); }
__device__ __forceinline__ float bfhi(unsigned u) { return __uint_as_float(u & 0xffff0000u); }
__device__ __forceinline__ unsigned f2bf(float f) {
    unsigned u = __float_as_uint(f);
    return (u + 0x7fffu + ((u >> 16) & 1u)) >> 16;
}

// ---------------- W prep: fp32 [K][N] -> fp16 transposed [N][K] ----------------

__global__ __launch_bounds__(256) void prep_w_kernel(const float* __restrict__ w0,
                                                     const float* __restrict__ w1,
                                                     const float* __restrict__ wc,
                                                     _Float16* __restrict__ Wt0,
                                                     _Float16* __restrict__ Wt1,
                                                     _Float16* __restrict__ Wtc) {
    int tx = threadIdx.x;
    if (blockIdx.x < 2) {
        const float* W = blockIdx.x ? w1 : w0;
        _Float16* T = blockIdx.x ? Wt1 : Wt0;
#pragma unroll
        for (int i = 0; i < 64; i++) {
            int e = tx + 256 * i;          // output index n*128+k (coalesced writes)
            int n = e >> 7, k = e & 127;
            T[e] = (_Float16)W[k * 128 + n];
        }
    } else {
        // cls_w [128][40] -> Wtc [48][128], zero-padded cols 40..47
#pragma unroll
        for (int i = 0; i < 24; i++) {
            int e = tx + 256 * i;          // n*128+k, n<48
            int n = e >> 7, k = e & 127;
            Wtc[e] = (_Float16)((n < NC) ? wc[k * NC + n] : 0.f);
        }
    }
}

// ---------------- MFMA fp16 GEMM body: hb = bf16((A @ W) [* dis]) ----------------
// Per wave: 16 rows x 128 cols. A-frag: lane holds A[rowBase + (l&15)][8*(l>>4)+i],
// W-frag: Wt[16*t + (l&15)][same k slots]. A/B share one slot->k bijection, so the
// result is layout-map invariant; C/D layout per learn_hip m89.
// hb pair layout: uint at [r*64 + c] = features (c, c+64) of row r.
// dis == nullptr -> unscaled (layer 1; dis unknown while fill runs concurrently).

__device__ __forceinline__ void gemm_mfma_body(int rowBase, const float* __restrict__ A,
                                               int lda, const _Float16* __restrict__ Wt,
                                               const float* __restrict__ dis,
                                               unsigned* __restrict__ hbU) {
    if (rowBase >= N_NODES) return;
    int lane = threadIdx.x & 63;
    int q = lane & 15, g = lane >> 4;

    const float* ap = A + (size_t)(rowBase + q) * lda + 8 * g;
    half8 a[4];
#pragma unroll
    for (int s = 0; s < 4; s++) {
        float4 lo = *(const float4*)(ap + 32 * s);
        float4 hi = *(const float4*)(ap + 32 * s + 4);
        half8 h;
        h[0] = (_Float16)lo.x; h[1] = (_Float16)lo.y;
        h[2] = (_Float16)lo.z; h[3] = (_Float16)lo.w;
        h[4] = (_Float16)hi.x; h[5] = (_Float16)hi.y;
        h[6] = (_Float16)hi.z; h[7] = (_Float16)hi.w;
        a[s] = h;
    }

    f32x4 acc[8];
#pragma unroll
    for (int t = 0; t < 8; t++) acc[t] = (f32x4){0.f, 0.f, 0.f, 0.f};

    const _Float16* wp = Wt + (size_t)q * 128 + 8 * g;
#pragma unroll
    for (int t = 0; t < 8; t++) {
#pragma unroll
        for (int s = 0; s < 4; s++) {
            half8 b = *(const half8*)(wp + (size_t)t * 2048 + 32 * s);
            acc[t] = __builtin_amdgcn_mfma_f32_16x16x32_f16(a[s], b, acc[t], 0, 0, 0);
        }
    }

#pragma unroll
    for (int j = 0; j < 4; j++) {
        int r = rowBase + 4 * g + j;          // C/D: row = 4*(l>>4)+reg, col = l&15
        float sc = dis ? dis[r] : 1.0f;
#pragma unroll
        for (int t = 0; t < 4; t++) {
            unsigned u = f2bf(acc[t][j] * sc) | (f2bf(acc[t + 4][j] * sc) << 16);
            hbU[(size_t)r * 64 + 16 * t + q] = u;
        }
    }
}

// ---------------- fused: MFMA gemm1 + XCD-windowed bucket fill ----------------
// Fill block handles destination range (bid&7)*XRANGE: dispatch round-robins blocks
// over the 8 XCDs, so each XCD writes only its own 3.2 MB adj2 slice (< 4 MB L2)
// -> partial-line scatter writes merge in L2 and write back once. Any (xcd,chunk)
// pair occurs exactly once -> correctness independent of actual block->XCD mapping.
// Edge loads via int4 (4 edges/instr, perfectly coalesced; N_EDGES % 4 == 0).

__global__ __launch_bounds__(256) void gemm_fill_kernel(const float* __restrict__ x,
                                                        const _Float16* __restrict__ Wt0,
                                                        unsigned* __restrict__ hbU,
                                                        const int* __restrict__ ei,
                                                        int* __restrict__ cnt,
                                                        int* __restrict__ adj2) {
    int tx = threadIdx.x;
    if (blockIdx.x < MF_BLOCKS) {
        int rowBase = (blockIdx.x * 4 + (tx >> 6)) * 16;
        gemm_mfma_body(rowBase, x, 128, Wt0, nullptr, hbU);
    } else {
        int fid = blockIdx.x - MF_BLOCKS;
        int xcd = blockIdx.x & 7;            // bind dest window to (heuristic) HW XCD
        int chunk = fid >> 3;
        int lo = xcd * XRANGE, hi = lo + XRANGE;
#pragma unroll
        for (int hgrp = 0; hgrp < 2; hgrp++) {
            int e0 = chunk * FILL_CHUNK + 1024 * hgrp + 4 * tx;
            if (e0 + 3 < N_EDGES) {
                int4 c = *(const int4*)&ei[N_EDGES + e0];
                int4 r = *(const int4*)&ei[e0];
                if (c.x >= lo && c.x < hi) {
                    int pos = atomicAdd(&cnt[c.x], 1);
                    if (pos < CAP) adj2[c.x * CAP + pos] = r.x;
                }
                if (c.y >= lo && c.y < hi) {
                    int pos = atomicAdd(&cnt[c.y], 1);
                    if (pos < CAP) adj2[c.y * CAP + pos] = r.y;
                }
                if (c.z >= lo && c.z < hi) {
                    int pos = atomicAdd(&cnt[c.z], 1);
                    if (pos < CAP) adj2[c.z * CAP + pos] = r.z;
                }
                if (c.w >= lo && c.w < hi) {
                    int pos = atomicAdd(&cnt[c.w], 1);
                    if (pos < CAP) adj2[c.w * CAP + pos] = r.w;
                }
            }
        }
    }
}

// ---------------- dis = rsqrt(deg+1) AND in-place hb *= dis (layer-1 prescale) ----

__global__ __launch_bounds__(256) void disscale_kernel(const int* __restrict__ cnt,
                                                       float* __restrict__ dis,
                                                       unsigned* __restrict__ hbU) {
    int r = blockIdx.x * 4 + (threadIdx.x >> 6);
    int lane = threadIdx.x & 63;
    float dc = rsqrtf((float)cnt[r] + 1.0f);
    if (lane == 0) dis[r] = dc;
    size_t idx = (size_t)r * 64 + lane;
    unsigned u = hbU[idx];
    hbU[idx] = f2bf(dc * bflo(u)) | (f2bf(dc * bfhi(u)) << 16);
}

// ---------------- standalone MFMA gemm (layer 2, dis-prescaled epilogue) ----------

__global__ __launch_bounds__(256) void gemm_mfma_kernel(const float* __restrict__ A, int lda,
                                                        const _Float16* __restrict__ Wt,
                                                        const float* __restrict__ dis,
                                                        unsigned* __restrict__ hbU) {
    int rowBase = (blockIdx.x * 4 + (int)(threadIdx.x >> 6)) * 16;
    gemm_mfma_body(rowBase, A, lda, Wt, dis, hbU);
}

// ---------------- aggregation (uint4 4-row-interleaved gather) ----------------
// hb rows PRE-SCALED by dis[src] -> per edge = pure add. One wave per node.
// Entry list av2: entry 0 = self node, entries 1..deg = adjacency (shifted load).
// Batch b covers 8 entries: lane group g = lane>>4 handles entries 8b+g and 8b+g+4;
// lane loads uint4 (16B) = uints [4q,4q+4) of the source row (q = lane&15).
// Invalid entries -> zero row at hb[N_NODES] (index cndmask only; loads give 0).
// Epilogue: shfl_xor(16,32) cross-group reduce; groups 0/1 write float4 lo/hi.
// out = relu(dc * sum + b).

__global__ __launch_bounds__(256) void agg_kernel(const unsigned* __restrict__ hb,
                                                  const float* __restrict__ dis,
                                                  const int* __restrict__ cnt,
                                                  const int* __restrict__ adj2,
                                                  const float* __restrict__ bias,
                                                  float* __restrict__ out, int ldo) {
    int node = __builtin_amdgcn_readfirstlane(blockIdx.x * 4 + (threadIdx.x >> 6));
    int lane = threadIdx.x & 63;
    int q = lane & 15, g = lane >> 4;

    // entry list (self + adj), lane-indexed
    int av2 = adj2[node * CAP + lane - 1];          // lane 0 reads bucket[-1]: unused
    if (lane == 0) av2 = node;
    int deg = __builtin_amdgcn_readfirstlane(cnt[node]);
    if (deg > 63) deg = 63;
    int n = deg + 1;                                // total entries (incl. self)
    int nb = (n + 7) >> 3;                          // 8 entries per batch

    const uint4* hb4 = (const uint4*)hb;            // row r = hb4[r*16 + q]

    float accL[4] = {0.f, 0.f, 0.f, 0.f};
    float accH[4] = {0.f, 0.f, 0.f, 0.f};

    uint4 vA1, vA2, vB1, vB2;
    {
        int e1 = g;
        int s1 = __shfl(av2, e1, 64);
        int s2 = __shfl(av2, e1 + 4, 64);
        s1 = (e1 < n) ? s1 : N_NODES;
        s2 = (e1 + 4 < n) ? s2 : N_NODES;
        vA1 = hb4[(size_t)s1 * 16 + q];
        vA2 = hb4[(size_t)s2 * 16 + q];
    }
    for (int b = 1; b < nb; b++) {
        int e1 = (b << 3) + g;
        int s1 = __shfl(av2, e1, 64);
        int s2 = __shfl(av2, e1 + 4, 64);
        s1 = (e1 < n) ? s1 : N_NODES;
        s2 = (e1 + 4 < n) ? s2 : N_NODES;
        vB1 = hb4[(size_t)s1 * 16 + q];
        vB2 = hb4[(size_t)s2 * 16 + q];

        accL[0] += bflo(vA1.x); accH[0] += bfhi(vA1.x);
        accL[1] += bflo(vA1.y); accH[1] += bfhi(vA1.y);
        accL[2] += bflo(vA1.z); accH[2] += bfhi(vA1.z);
        accL[3] += bflo(vA1.w); accH[3] += bfhi(vA1.w);
        accL[0] += bflo(vA2.x); accH[0] += bfhi(vA2.x);
        accL[1] += bflo(vA2.y); accH[1] += bfhi(vA2.y);
        accL[2] += bflo(vA2.z); accH[2] += bfhi(vA2.z);
        accL[3] += bflo(vA2.w); accH[3] += bfhi(vA2.w);
        vA1 = vB1; vA2 = vB2;
    }
    accL[0] += bflo(vA1.x); accH[0] += bfhi(vA1.x);
    accL[1] += bflo(vA1.y); accH[1] += bfhi(vA1.y);
    accL[2] += bflo(vA1.z); accH[2] += bfhi(vA1.z);
    accL[3] += bflo(vA1.w); accH[3] += bfhi(vA1.w);
    accL[0] += bflo(vA2.x); accH[0] += bfhi(vA2.x);
    accL[1] += bflo(vA2.y); accH[1] += bfhi(vA2.y);
    accL[2] += bflo(vA2.z); accH[2] += bfhi(vA2.z);
    accL[3] += bflo(vA2.w); accH[3] += bfhi(vA2.w);

    // cross-group reduce: lanes {l, l^16, l^32, l^48} hold partials of chunk q
#pragma unroll
    for (int k = 0; k < 4; k++) {
        accL[k] += __shfl_xor(accL[k], 16, 64);
        accL[k] += __shfl_xor(accL[k], 32, 64);
        accH[k] += __shfl_xor(accH[k], 16, 64);
        accH[k] += __shfl_xor(accH[k], 32, 64);
    }

    float dc = dis[node];
    if (g == 0) {
        float4 bi = *(const float4*)&bias[4 * q];
        float4 r;
        r.x = fmaxf(fmaf(dc, accL[0], bi.x), 0.f);
        r.y = fmaxf(fmaf(dc, accL[1], bi.y), 0.f);
        r.z = fmaxf(fmaf(dc, accL[2], bi.z), 0.f);
        r.w = fmaxf(fmaf(dc, accL[3], bi.w), 0.f);
        *(float4*)&out[(size_t)node * ldo + 4 * q] = r;
    } else if (g == 1) {
        float4 bi = *(const float4*)&bias[64 + 4 * q];
        float4 r;
        r.x = fmaxf(fmaf(dc, accH[0], bi.x), 0.f);
        r.y = fmaxf(fmaf(dc, accH[1], bi.y), 0.f);
        r.z = fmaxf(fmaf(dc, accH[2], bi.z), 0.f);
        r.w = fmaxf(fmaf(dc, accH[3], bi.w), 0.f);
        *(float4*)&out[(size_t)node * ldo + 64 + 4 * q] = r;
    }
}

// ---------------- classifier (MFMA, 3 col-tiles of 16, cols 40..47 masked) ----------------

__global__ __launch_bounds__(256) void classifier_kernel(const float* __restrict__ A, int lda,
                                                         const _Float16* __restrict__ Wtc,
                                                         const float* __restrict__ bc,
                                                         float* __restrict__ out1,
                                                         float* __restrict__ out2) {
    int rowBase = (blockIdx.x * 4 + (int)(threadIdx.x >> 6)) * 16;
    if (rowBase >= N_NODES) return;
    int lane = threadIdx.x & 63;
    int q = lane & 15, g = lane >> 4;

    const float* ap = A + (size_t)(rowBase + q) * lda + 8 * g;
    half8 a[4];
#pragma unroll
    for (int s = 0; s < 4; s++) {
        float4 lo = *(const float4*)(ap + 32 * s);
        float4 hi = *(const float4*)(ap + 32 * s + 4);
        half8 h;
        h[0] = (_Float16)lo.x; h[1] = (_Float16)lo.y;
        h[2] = (_Float16)lo.z; h[3] = (_Float16)lo.w;
        h[4] = (_Float16)hi.x; h[5] = (_Float16)hi.y;
        h[6] = (_Float16)hi.z; h[7] = (_Float16)hi.w;
        a[s] = h;
    }

    f32x4 acc[3];
#pragma unroll
    for (int t = 0; t < 3; t++) acc[t] = (f32x4){0.f, 0.f, 0.f, 0.f};

    const _Float16* wp = Wtc + (size_t)q * 128 + 8 * g;
#pragma unroll
    for (int t = 0; t < 3; t++) {
#pragma unroll
        for (int s = 0; s < 4; s++) {
            half8 b = *(const half8*)(wp + (size_t)t * 2048 + 32 * s);
            acc[t] = __builtin_amdgcn_mfma_f32_16x16x32_f16(a[s], b, acc[t], 0, 0, 0);
        }
    }

#pragma unroll
    for (int j = 0; j < 4; j++) {
        int r = rowBase + 4 * g + j;
#pragma unroll
        for (int t = 0; t < 3; t++) {
            int c = 16 * t + q;
            if (c < NC) {
                float v = acc[t][j] + bc[c];
                out1[(size_t)r * NC + c] = v;
                out2[(size_t)r * 296 + c] = v;
            }
        }
    }
}

// ---------------- launch ----------------

extern "C" void kernel_launch(void* const* d_in, const int* in_sizes, int n_in,
                              void* d_out, int out_size, void* d_ws, size_t ws_size,
                              hipStream_t stream) {
    (void)in_sizes; (void)n_in; (void)out_size; (void)ws_size;

    const float* x     = (const float*)d_in[0];
    const int*   ei    = (const int*)d_in[1];
    const float* w0    = (const float*)d_in[2];
    const float* b0    = (const float*)d_in[3];
    const float* w1    = (const float*)d_in[4];
    const float* b1    = (const float*)d_in[5];
    const float* cls_w = (const float*)d_in[6];
    const float* cls_b = (const float*)d_in[7];

    float* logits = (float*)d_out;
    float* feat   = logits + (size_t)N_NODES * NC;   // [N,296]: h1 | h2 | logits

    char* ws = (char*)d_ws;
    int*       cnt  = (int*)(ws + 0);                 // 400 KB
    float*     dis  = (float*)(ws + 400000);          // 400 KB
    int*       adj2 = (int*)(ws + 800000);            // 25.6 MB (100K x 64)
    unsigned*  hbU  = (unsigned*)(ws + 26400000);     // 25.6 MB + 256B zero row
    _Float16*  Wt0  = (_Float16*)(ws + 52032768);     // 32 KB
    _Float16*  Wt1  = (_Float16*)(ws + 52065536);     // 32 KB
    _Float16*  Wtc  = (_Float16*)(ws + 52098304);     // 12 KB

    hipMemsetAsync(cnt, 0, (size_t)N_NODES * 4, stream);
    hipMemsetAsync(hbU + (size_t)N_NODES * 64, 0, 256, stream);   // zero row (gather pad)

    prep_w_kernel<<<3, 256, 0, stream>>>(w0, w1, cls_w, Wt0, Wt1, Wtc);

    // fused: layer-1 MFMA GEMM (first 1563 blocks) + XCD-windowed bucket fill
    gemm_fill_kernel<<<MF_BLOCKS + FILL_BLOCKS, 256, 0, stream>>>(
        x, Wt0, hbU, ei, cnt, adj2);

    // dis + in-place layer-1 prescale of hb
    disscale_kernel<<<N_NODES / 4, 256, 0, stream>>>(cnt, dis, hbU);

    agg_kernel<<<N_NODES / 4, 256, 0, stream>>>(hbU, dis, cnt, adj2, b0, feat + 0, 296);
    gemm_mfma_kernel<<<MF_BLOCKS, 256, 0, stream>>>(feat, 296, Wt1, dis, hbU);
    agg_kernel<<<N_NODES / 4, 256, 0, stream>>>(hbU, dis, cnt, adj2, b1, feat + 128, 296);
    classifier_kernel<<<MF_BLOCKS, 256, 0, stream>>>(feat + 128, 296, Wtc, cls_b,
                                                     logits, feat + 256);
}

// Round 5
// 460.499 us; speedup vs baseline: 1.0522x; 1.0522x over previous
//
#include <hip/hip_runtime.h>
#include <hip/hip_bf16.h>

#define N_NODES 100000
#define N_EDGES 1600000
#define NC 40
#define CAP 64               // bucket capacity; data max-degree ~45 << 64

#define NXCD 8
#define XRANGE 12500         // N_NODES / NXCD : destination slice per XCD
#define FILL_CHUNK  2048     // edges per block (256 thr x 8)
#define FILL_CHUNKS 782      // ceil(N_EDGES/FILL_CHUNK)
#define FILL_BLOCKS (NXCD * FILL_CHUNKS)   // 6256
#define MF_BLOCKS 1563       // ceil(100000 / 64): 64 rows/block = 4 waves x 16 rows
#define FB_BLOCKS 6250       // fused agg blocks: 16 nodes each (100000/16)

typedef _Float16 half8 __attribute__((ext_vector_type(8)));
typedef float f32x4 __attribute__((ext_vector_type(4)));

// ---- bf16 helpers (packed 2x16 in a uint) ----
__device__ __forceinline__ float bflo(unsigned u) { return __uint_as_float(u << 16); }
__device__ __forceinline__ float bfhi(unsigned u) { return __uint_as_float(u & 0xffff0000u); }
__device__ __forceinline__ unsigned f2bf(float f) {
    unsigned u = __float_as_uint(f);
    return (u + 0x7fffu + ((u >> 16) & 1u)) >> 16;
}

// ---------------- W prep: fp32 [K][N] -> fp16 transposed [N][K] ----------------

__global__ __launch_bounds__(256) void prep_w_kernel(const float* __restrict__ w0,
                                                     const float* __restrict__ w1,
                                                     const float* __restrict__ wc,
                                                     _Float16* __restrict__ Wt0,
                                                     _Float16* __restrict__ Wt1,
                                                     _Float16* __restrict__ Wtc) {
    int tx = threadIdx.x;
    if (blockIdx.x < 2) {
        const float* W = blockIdx.x ? w1 : w0;
        _Float16* T = blockIdx.x ? Wt1 : Wt0;
#pragma unroll
        for (int i = 0; i < 64; i++) {
            int e = tx + 256 * i;          // output index n*128+k (coalesced writes)
            int n = e >> 7, k = e & 127;
            T[e] = (_Float16)W[k * 128 + n];
        }
    } else {
        // cls_w [128][40] -> Wtc [48][128], zero-padded cols 40..47
#pragma unroll
        for (int i = 0; i < 24; i++) {
            int e = tx + 256 * i;          // n*128+k, n<48
            int n = e >> 7, k = e & 127;
            Wtc[e] = (_Float16)((n < NC) ? wc[k * NC + n] : 0.f);
        }
    }
}

// ---------------- MFMA fp16 GEMM body: hb = bf16((A @ W) [* dis]) ----------------
// Per wave: 16 rows x 128 cols. A-frag: lane holds A[rowBase + (l&15)][8*(l>>4)+i],
// W-frag: Wt[16*t + (l&15)][same k slots]. A/B share one slot->k bijection, so the
// result is layout-map invariant; C/D layout per learn_hip m89.
// hb pair layout: uint at [r*64 + c] = features (c, c+64) of row r.
// dis == nullptr -> unscaled (layer 1; dis unknown while fill runs concurrently).

__device__ __forceinline__ void gemm_mfma_body(int rowBase, const float* __restrict__ A,
                                               int lda, const _Float16* __restrict__ Wt,
                                               const float* __restrict__ dis,
                                               unsigned* __restrict__ hbU) {
    if (rowBase >= N_NODES) return;
    int lane = threadIdx.x & 63;
    int q = lane & 15, g = lane >> 4;

    const float* ap = A + (size_t)(rowBase + q) * lda + 8 * g;
    half8 a[4];
#pragma unroll
    for (int s = 0; s < 4; s++) {
        float4 lo = *(const float4*)(ap + 32 * s);
        float4 hi = *(const float4*)(ap + 32 * s + 4);
        half8 h;
        h[0] = (_Float16)lo.x; h[1] = (_Float16)lo.y;
        h[2] = (_Float16)lo.z; h[3] = (_Float16)lo.w;
        h[4] = (_Float16)hi.x; h[5] = (_Float16)hi.y;
        h[6] = (_Float16)hi.z; h[7] = (_Float16)hi.w;
        a[s] = h;
    }

    f32x4 acc[8];
#pragma unroll
    for (int t = 0; t < 8; t++) acc[t] = (f32x4){0.f, 0.f, 0.f, 0.f};

    const _Float16* wp = Wt + (size_t)q * 128 + 8 * g;
#pragma unroll
    for (int t = 0; t < 8; t++) {
#pragma unroll
        for (int s = 0; s < 4; s++) {
            half8 b = *(const half8*)(wp + (size_t)t * 2048 + 32 * s);
            acc[t] = __builtin_amdgcn_mfma_f32_16x16x32_f16(a[s], b, acc[t], 0, 0, 0);
        }
    }

#pragma unroll
    for (int j = 0; j < 4; j++) {
        int r = rowBase + 4 * g + j;          // C/D: row = 4*(l>>4)+reg, col = l&15
        float sc = dis ? dis[r] : 1.0f;
#pragma unroll
        for (int t = 0; t < 4; t++) {
            unsigned u = f2bf(acc[t][j] * sc) | (f2bf(acc[t + 4][j] * sc) << 16);
            hbU[(size_t)r * 64 + 16 * t + q] = u;
        }
    }
}

// ---------------- fused: MFMA gemm1 + XCD-windowed bucket fill ----------------
// Fill block handles destination range (bid&7)*XRANGE: dispatch round-robins blocks
// over the 8 XCDs, so each XCD writes only its own 3.2 MB adj2 slice (< 4 MB L2)
// -> partial-line scatter writes merge in L2 and write back once. Any (xcd,chunk)
// pair occurs exactly once -> correctness independent of actual block->XCD mapping.
// (R3-proven scalar 8-edge loop; the R4 int4 variant measured slower.)

__global__ __launch_bounds__(256) void gemm_fill_kernel(const float* __restrict__ x,
                                                        const _Float16* __restrict__ Wt0,
                                                        unsigned* __restrict__ hbU,
                                                        const int* __restrict__ ei,
                                                        int* __restrict__ cnt,
                                                        int* __restrict__ adj2) {
    int tx = threadIdx.x;
    if (blockIdx.x < MF_BLOCKS) {
        int rowBase = (blockIdx.x * 4 + (tx >> 6)) * 16;
        gemm_mfma_body(rowBase, x, 128, Wt0, nullptr, hbU);
    } else {
        int fid = blockIdx.x - MF_BLOCKS;
        int xcd = blockIdx.x & 7;            // bind dest window to (heuristic) HW XCD
        int chunk = fid >> 3;
        int lo = xcd * XRANGE, hi = lo + XRANGE;
        int base = chunk * FILL_CHUNK + tx;
        int c[8], r[8];
#pragma unroll
        for (int j = 0; j < 8; j++) {
            int e = base + 256 * j;
            c[j] = (e < N_EDGES) ? ei[N_EDGES + e] : -1;
            r[j] = (e < N_EDGES) ? ei[e] : 0;
        }
#pragma unroll
        for (int j = 0; j < 8; j++) {
            if (c[j] >= lo && c[j] < hi) {
                int pos = atomicAdd(&cnt[c[j]], 1);
                if (pos < CAP) adj2[c[j] * CAP + pos] = r[j];
            }
        }
    }
}

// ---------------- dis = rsqrt(deg+1) AND in-place hb *= dis (layer-1 prescale) ----

__global__ __launch_bounds__(256) void disscale_kernel(const int* __restrict__ cnt,
                                                       float* __restrict__ dis,
                                                       unsigned* __restrict__ hbU) {
    int r = blockIdx.x * 4 + (threadIdx.x >> 6);
    int lane = threadIdx.x & 63;
    float dc = rsqrtf((float)cnt[r] + 1.0f);
    if (lane == 0) dis[r] = dc;
    size_t idx = (size_t)r * 64 + lane;
    unsigned u = hbU[idx];
    hbU[idx] = f2bf(dc * bflo(u)) | (f2bf(dc * bfhi(u)) << 16);
}

// ---------------- agg core (R3-proven): sum of self + neighbor rows ----------------
// hb rows PRE-SCALED by dis[src] -> per edge = pure add. Pipelined batches of 8
// broadcast-row gathers (index via readlane, wave-uniform); tail value-masked,
// padded gathers target own row (no zero row needed). Lane holds feats (lane,lane+64).

__device__ __forceinline__ void agg_core(const unsigned* __restrict__ hb,
                                         const int* __restrict__ cnt,
                                         const int* __restrict__ adj2,
                                         int node, int lane,
                                         float& outL, float& outH) {
    int av = adj2[node * CAP + lane];          // whole adjacency list, lane-indexed
    int deg = __builtin_amdgcn_readfirstlane(cnt[node]);
    if (deg > CAP) deg = CAP;

    unsigned sv = hb[(size_t)node * 64 + lane];
    float aL[4], aH[4];
    aL[0] = bflo(sv); aH[0] = bfhi(sv);        // self term (already dis-scaled)
    aL[1] = aL[2] = aL[3] = 0.f;
    aH[1] = aH[2] = aH[3] = 0.f;

    if (deg > 0) {
        unsigned vA[8];
        int baseA = 0;
#pragma unroll
        for (int j = 0; j < 8; j++) {
            int s = (j < deg) ? __builtin_amdgcn_readlane(av, j) : node;
            vA[j] = hb[(size_t)s * 64 + lane];
        }
        int nb = (deg + 7) >> 3;
        for (int b = 1; b < nb; b++) {
            unsigned vB[8];
            int baseB = b << 3;
#pragma unroll
            for (int j = 0; j < 8; j++) {
                int e = baseB + j;
                int s = (e < deg) ? __builtin_amdgcn_readlane(av, e) : node;
                vB[j] = hb[(size_t)s * 64 + lane];
            }
            // batch b-1 is always full (b-1 < nb-1  =>  8b <= deg)
#pragma unroll
            for (int j = 0; j < 8; j++) {
                aL[j & 3] += bflo(vA[j]);
                aH[j & 3] += bfhi(vA[j]);
            }
#pragma unroll
            for (int j = 0; j < 8; j++) vA[j] = vB[j];
            baseA = baseB;
        }
#pragma unroll
        for (int j = 0; j < 8; j++) {
            float xx = (baseA + j < deg) ? bflo(vA[j]) : 0.f;
            float yy = (baseA + j < deg) ? bfhi(vA[j]) : 0.f;
            aL[j & 3] += xx;
            aH[j & 3] += yy;
        }
    }
    outL = (aL[0] + aL[1]) + (aL[2] + aL[3]);
    outH = (aH[0] + aH[1]) + (aH[2] + aH[3]);
}

// ---------------- fused agg1 + gemm2: h1 = relu(dc*sum+b0) -> feat & LDS;
// then hb2 = bf16(dis * (h1 @ W1)) straight from LDS (no feat re-read).
// Block = 16 nodes (4 waves x 4 sequential aggs). LDS row padded to 136 halves
// (272B) -> MFMA ds_read_b128 lands 2-way bank aliasing (free).
// Wave w computes col-tiles {w, w+4} = packed pair columns 16w..16w+15.
// hb2 MUST be a distinct buffer (other blocks still gather hb1 concurrently).

__global__ __launch_bounds__(256) void agg_gemm_kernel(const unsigned* __restrict__ hb,
                                                       const float* __restrict__ dis,
                                                       const int* __restrict__ cnt,
                                                       const int* __restrict__ adj2,
                                                       const float* __restrict__ bias,
                                                       const _Float16* __restrict__ Wt,
                                                       float* __restrict__ out,
                                                       unsigned* __restrict__ hb2) {
    __shared__ _Float16 Hs[16][136];
    int w = threadIdx.x >> 6;
    int lane = threadIdx.x & 63;
    int rowBase = blockIdx.x * 16;

#pragma unroll
    for (int i = 0; i < 4; i++) {
        int node = rowBase + w * 4 + i;
        float sL, sH;
        agg_core(hb, cnt, adj2, node, lane, sL, sH);
        float dc = dis[node];
        float r0 = fmaxf(fmaf(dc, sL, bias[lane]), 0.f);
        float r1 = fmaxf(fmaf(dc, sH, bias[lane + 64]), 0.f);
        out[(size_t)node * 296 + lane] = r0;
        out[(size_t)node * 296 + 64 + lane] = r1;
        Hs[w * 4 + i][lane] = (_Float16)r0;
        Hs[w * 4 + i][lane + 64] = (_Float16)r1;
    }
    __syncthreads();

    int q = lane & 15, g = lane >> 4;
    half8 a[4];
#pragma unroll
    for (int s = 0; s < 4; s++) a[s] = *(const half8*)&Hs[q][8 * g + 32 * s];

    f32x4 acc0 = (f32x4){0.f, 0.f, 0.f, 0.f};
    f32x4 acc1 = (f32x4){0.f, 0.f, 0.f, 0.f};
    const _Float16* wp = Wt + (size_t)q * 128 + 8 * g;
#pragma unroll
    for (int s = 0; s < 4; s++) {
        half8 bA = *(const half8*)(wp + (size_t)w * 2048 + 32 * s);
        half8 bB = *(const half8*)(wp + (size_t)(w + 4) * 2048 + 32 * s);
        acc0 = __builtin_amdgcn_mfma_f32_16x16x32_f16(a[s], bA, acc0, 0, 0, 0);
        acc1 = __builtin_amdgcn_mfma_f32_16x16x32_f16(a[s], bB, acc1, 0, 0, 0);
    }
#pragma unroll
    for (int j = 0; j < 4; j++) {
        int r = rowBase + 4 * g + j;
        float sc = dis[r];
        unsigned u = f2bf(acc0[j] * sc) | (f2bf(acc1[j] * sc) << 16);
        hb2[(size_t)r * 64 + 16 * w + q] = u;
    }
}

// ---------------- fused agg2 + classifier ----------------
// h2 = relu(dc*sum+b1) -> feat[128..256) & LDS; waves 0..2 each do one 16-col
// NC-tile of the classifier from LDS (cols 40..47 masked); logits + feat tail.
// Reads hb2 only (read-only here) -> safe for in-place small-ws path too.

__global__ __launch_bounds__(256) void agg_cls_kernel(const unsigned* __restrict__ hb2,
                                                      const float* __restrict__ dis,
                                                      const int* __restrict__ cnt,
                                                      const int* __restrict__ adj2,
                                                      const float* __restrict__ bias,
                                                      const _Float16* __restrict__ Wtc,
                                                      const float* __restrict__ bc,
                                                      float* __restrict__ feat,
                                                      float* __restrict__ logits) {
    __shared__ _Float16 Hs[16][136];
    int w = threadIdx.x >> 6;
    int lane = threadIdx.x & 63;
    int rowBase = blockIdx.x * 16;

#pragma unroll
    for (int i = 0; i < 4; i++) {
        int node = rowBase + w * 4 + i;
        float sL, sH;
        agg_core(hb2, cnt, adj2, node, lane, sL, sH);
        float dc = dis[node];
        float r0 = fmaxf(fmaf(dc, sL, bias[lane]), 0.f);
        float r1 = fmaxf(fmaf(dc, sH, bias[lane + 64]), 0.f);
        feat[(size_t)node * 296 + 128 + lane] = r0;
        feat[(size_t)node * 296 + 192 + lane] = r1;
        Hs[w * 4 + i][lane] = (_Float16)r0;
        Hs[w * 4 + i][lane + 64] = (_Float16)r1;
    }
    __syncthreads();

    if (w < 3) {
        int q = lane & 15, g = lane >> 4;
        half8 a[4];
#pragma unroll
        for (int s = 0; s < 4; s++) a[s] = *(const half8*)&Hs[q][8 * g + 32 * s];

        f32x4 acc = (f32x4){0.f, 0.f, 0.f, 0.f};
        const _Float16* wp = Wtc + (size_t)(16 * w + q) * 128 + 8 * g;
#pragma unroll
        for (int s = 0; s < 4; s++) {
            half8 b = *(const half8*)(wp + 32 * s);
            acc = __builtin_amdgcn_mfma_f32_16x16x32_f16(a[s], b, acc, 0, 0, 0);
        }
        int c = 16 * w + q;
        if (c < NC) {
#pragma unroll
            for (int j = 0; j < 4; j++) {
                int r = rowBase + 4 * g + j;
                float v = acc[j] + bc[c];
                logits[(size_t)r * NC + c] = v;
                feat[(size_t)r * 296 + 256 + c] = v;
            }
        }
    }
}

// ---------------- small-ws fallback: standalone agg1 + in-place gemm2 ----------------

__global__ __launch_bounds__(256) void agg_kernel(const unsigned* __restrict__ hb,
                                                  const float* __restrict__ dis,
                                                  const int* __restrict__ cnt,
                                                  const int* __restrict__ adj2,
                                                  const float* __restrict__ bias,
                                                  float* __restrict__ out, int ldo) {
    int node = __builtin_amdgcn_readfirstlane(blockIdx.x * 4 + (threadIdx.x >> 6));
    int lane = threadIdx.x & 63;
    float sL, sH;
    agg_core(hb, cnt, adj2, node, lane, sL, sH);
    float dc = dis[node];
    out[(size_t)node * ldo + lane] = fmaxf(fmaf(dc, sL, bias[lane]), 0.f);
    out[(size_t)node * ldo + 64 + lane] = fmaxf(fmaf(dc, sH, bias[lane + 64]), 0.f);
}

__global__ __launch_bounds__(256) void gemm_mfma_kernel(const float* __restrict__ A, int lda,
                                                        const _Float16* __restrict__ Wt,
                                                        const float* __restrict__ dis,
                                                        unsigned* __restrict__ hbU) {
    int rowBase = (blockIdx.x * 4 + (int)(threadIdx.x >> 6)) * 16;
    gemm_mfma_body(rowBase, A, lda, Wt, dis, hbU);
}

// ---------------- launch ----------------

extern "C" void kernel_launch(void* const* d_in, const int* in_sizes, int n_in,
                              void* d_out, int out_size, void* d_ws, size_t ws_size,
                              hipStream_t stream) {
    (void)in_sizes; (void)n_in; (void)out_size;

    const float* x     = (const float*)d_in[0];
    const int*   ei    = (const int*)d_in[1];
    const float* w0    = (const float*)d_in[2];
    const float* b0    = (const float*)d_in[3];
    const float* w1    = (const float*)d_in[4];
    const float* b1    = (const float*)d_in[5];
    const float* cls_w = (const float*)d_in[6];
    const float* cls_b = (const float*)d_in[7];

    float* logits = (float*)d_out;
    float* feat   = logits + (size_t)N_NODES * NC;   // [N,296]: h1 | h2 | logits

    char* ws = (char*)d_ws;
    int*       cnt  = (int*)(ws + 0);                 // 400 KB
    float*     dis  = (float*)(ws + 400000);          // 400 KB
    int*       adj2 = (int*)(ws + 800000);            // 25.6 MB (100K x 64)
    unsigned*  hbU  = (unsigned*)(ws + 26400000);     // 25.6 MB bf16-pair matrix
    _Float16*  Wt0  = (_Float16*)(ws + 52000000);     // 32 KB
    _Float16*  Wt1  = (_Float16*)(ws + 52032768);     // 32 KB
    _Float16*  Wtc  = (_Float16*)(ws + 52065536);     // 12 KB
    // second hb buffer (fused agg1+gemm2 needs distinct produce/consume buffers)
    const size_t HB2_OFF = 52080000;                  // 16B-aligned
    const size_t NEEDED  = HB2_OFF + (size_t)N_NODES * 256;   // 77.68 MB
    bool big = (ws_size >= NEEDED);
    unsigned* hbU2 = big ? (unsigned*)(ws + HB2_OFF) : hbU;

    hipMemsetAsync(cnt, 0, (size_t)N_NODES * 4, stream);

    prep_w_kernel<<<3, 256, 0, stream>>>(w0, w1, cls_w, Wt0, Wt1, Wtc);

    // fused: layer-1 MFMA GEMM (first 1563 blocks) + XCD-windowed bucket fill
    gemm_fill_kernel<<<MF_BLOCKS + FILL_BLOCKS, 256, 0, stream>>>(
        x, Wt0, hbU, ei, cnt, adj2);

    // dis + in-place layer-1 prescale of hb
    disscale_kernel<<<N_NODES / 4, 256, 0, stream>>>(cnt, dis, hbU);

    if (big) {
        // agg1 fused with gemm2 (h1 -> LDS -> MFMA -> hb2), then agg2 fused with cls
        agg_gemm_kernel<<<FB_BLOCKS, 256, 0, stream>>>(hbU, dis, cnt, adj2, b0, Wt1,
                                                       feat, hbU2);
        agg_cls_kernel<<<FB_BLOCKS, 256, 0, stream>>>(hbU2, dis, cnt, adj2, b1, Wtc,
                                                      cls_b, feat, logits);
    } else {
        // fallback: serial agg1, in-place gemm2, fused agg2+cls
        agg_kernel<<<N_NODES / 4, 256, 0, stream>>>(hbU, dis, cnt, adj2, b0,
                                                    feat + 0, 296);
        gemm_mfma_kernel<<<MF_BLOCKS, 256, 0, stream>>>(feat, 296, Wt1, dis, hbU);
        agg_cls_kernel<<<FB_BLOCKS, 256, 0, stream>>>(hbU, dis, cnt, adj2, b1, Wtc,
                                                      cls_b, feat, logits);
    }
}